// Round 1
// baseline (121.283 us; speedup 1.0000x reference)
//
#include <hip/hip_runtime.h>
#include <hip/hip_bf16.h>

// Problem geometry (fixed by the reference)
#define BD   4
#define SD   8
#define LSEC 256
#define LL   254
#define DD   768
#define MAXS 100
#define TT   (SD*LL)   // 2032

// Flat output offsets (float32 elements, reference return order)
#define OFF_SF  0LL                       // sentence_feature [4,100,768]   307200
#define OFF_TM  307200LL                  // tran_mask        [4,2032,8]     65024
#define OFF_TMS 372224LL                  // tran_mask_sec    [4,100,8]       3200
#define OFF_SMF 375424LL                  // sentence_mask_full [4,2032,2032] 16516096
#define OFF_SEC (375424LL + 16516096LL)   // section_mask_full  [4,2032,2032] 16516096
#define OFF_LOG 33407616LL                // logits1 [4,2]

// ---------------------------------------------------------------------------
// Kernel A: per-doc prep — sentence ranges, tran_mask_sec, logits1
// ---------------------------------------------------------------------------
__global__ __launch_bounds__(256) void prep_kernel(
    const int*   __restrict__ ids_g,          // [B][T] sentence ids (1..100, non-decreasing)
    const float* __restrict__ pooled_feature, // [32][768]
    const float* __restrict__ W_cls,          // [2][768]
    const float* __restrict__ b_cls,          // [2]
    float* __restrict__ out,
    int*   __restrict__ wfirst,               // [B][MAXS]
    int*   __restrict__ wlast)                // [B][MAXS]
{
    const int b = blockIdx.x;
    const int tid = threadIdx.x;
    __shared__ int sm_ids[TT];
    __shared__ int s_counts[SD];
    __shared__ int s_starts[SD];
    __shared__ float red[256];

    for (int t = tid; t < TT; t += 256) sm_ids[t] = ids_g[b*TT + t];
    for (int s = tid; s < MAXS; s += 256) { wfirst[b*MAXS+s] = -1; wlast[b*MAXS+s] = -1; }
    __syncthreads();

    // ids come from cumsum -> contiguous runs; record run boundaries
    for (int t = tid; t < TT; t += 256) {
        int id = sm_ids[t];
        if (t == 0    || sm_ids[t-1] != id) wfirst[b*MAXS + id - 1] = t;
        if (t == TT-1 || sm_ids[t+1] != id) wlast [b*MAXS + id - 1] = t;
    }

    // distinct-id count per section via 101-bit bitset
    if (tid < SD) {
        unsigned long long m0 = 0, m1 = 0;
        for (int i = 0; i < LL; ++i) {
            int v = sm_ids[tid*LL + i];
            if (v < 64) m0 |= (1ull << v); else m1 |= (1ull << (v - 64));
        }
        s_counts[tid] = __popcll(m0) + __popcll(m1);
    }
    __syncthreads();
    if (tid == 0) {
        int acc = 0;
        for (int j = 0; j < SD; ++j) { s_starts[j] = acc; acc += s_counts[j]; }
    }
    __syncthreads();

    // tran_mask_sec [b][100][8]
    for (int idx = tid; idx < MAXS*SD; idx += 256) {
        int r = idx / SD, j = idx % SD;
        float v = (r >= s_starts[j] && r < s_starts[j] + s_counts[j]) ? 1.0f : 0.0f;
        out[OFF_TMS + (long long)b*(MAXS*SD) + idx] = v;
    }

    // logits1: max over sections of pooled_feature, dot with W_cls
    float acc0 = 0.f, acc1 = 0.f;
    #pragma unroll
    for (int k = 0; k < 3; ++k) {
        int d = tid + k*256;
        float mv = pooled_feature[(b*SD)*DD + d];
        #pragma unroll
        for (int j = 1; j < SD; ++j) mv = fmaxf(mv, pooled_feature[(b*SD + j)*DD + d]);
        acc0 += mv * W_cls[d];
        acc1 += mv * W_cls[DD + d];
    }
    red[tid] = acc0; __syncthreads();
    for (int off = 128; off > 0; off >>= 1) { if (tid < off) red[tid] += red[tid+off]; __syncthreads(); }
    float l0 = red[0];
    __syncthreads();
    red[tid] = acc1; __syncthreads();
    for (int off = 128; off > 0; off >>= 1) { if (tid < off) red[tid] += red[tid+off]; __syncthreads(); }
    if (tid == 0) {
        out[OFF_LOG + b*2 + 0] = l0     + b_cls[0];
        out[OFF_LOG + b*2 + 1] = red[0] + b_cls[1];
    }
}

// ---------------------------------------------------------------------------
// Kernel B: per-sentence max pooling over its contiguous token range
// ---------------------------------------------------------------------------
__global__ __launch_bounds__(256) void pool_kernel(
    const float* __restrict__ atf,     // [32][256][768]
    const int*   __restrict__ wfirst,
    const int*   __restrict__ wlast,
    float* __restrict__ pooled)        // [400][768]
{
    const int blk = blockIdx.x;        // b*100 + s
    const int b = blk / MAXS;
    const int tid = threadIdx.x;
    int f = wfirst[blk], l = wlast[blk];
    float a0, a1, a2;
    if (f < 0) { a0 = a1 = a2 = 0.f; } // absent sentence id -> zero (ref: isfinite mask)
    else {
        a0 = a1 = a2 = -INFINITY;
        for (int t = f; t <= l; ++t) {
            const float* row = atf + ((long long)(b*SD + t / LL) * LSEC + 1 + t % LL) * DD;
            a0 = fmaxf(a0, row[tid]);
            a1 = fmaxf(a1, row[tid + 256]);
            a2 = fmaxf(a2, row[tid + 512]);
        }
    }
    float* orow = pooled + (long long)blk * DD;
    orow[tid] = a0; orow[tid + 256] = a1; orow[tid + 512] = a2;
}

// ---------------------------------------------------------------------------
// Kernel C: sentence_feature = pooled [400,768] @ W_g2[e,d]^T -> [400,768]
// Tile: 16 rows x 128 cols, K-tile 64, f32 VALU, float4 LDS, pad 68 (+4)
// ---------------------------------------------------------------------------
__global__ __launch_bounds__(256) void sf_gemm_kernel(
    const float* __restrict__ pooled,  // [400][768]
    const float* __restrict__ Wg2,     // [768][768] row-major [e][d]
    float* __restrict__ out)
{
    const int r0 = blockIdx.x * 16;    // 25 blocks
    const int e0 = blockIdx.y * 128;   // 6 blocks
    const int tid = threadIdx.x;
    __shared__ __align__(16) float As[16][68];
    __shared__ __align__(16) float Ws[128][68];
    const int er = tid & 31;
    const int sr = tid >> 5;           // 0..7
    float acc[2][4] = {{0.f,0.f,0.f,0.f},{0.f,0.f,0.f,0.f}};

    for (int k0 = 0; k0 < DD; k0 += 64) {
        {   // stage A: 16x64 = 256 float4, one per thread
            int i = tid >> 4, c4 = (tid & 15) * 4;
            *(float4*)&As[i][c4] = *(const float4*)&pooled[(long long)(r0 + i)*DD + k0 + c4];
        }
        #pragma unroll
        for (int it = 0; it < 8; ++it) {   // stage W: 128x64 = 2048 float4 / 256
            int idx = tid + it*256;
            int row = idx >> 4, c4 = (idx & 15) * 4;
            *(float4*)&Ws[row][c4] = *(const float4*)&Wg2[(long long)(e0 + row)*DD + k0 + c4];
        }
        __syncthreads();
        #pragma unroll
        for (int k = 0; k < 64; k += 4) {
            float4 a0 = *(float4*)&As[2*sr][k];
            float4 a1 = *(float4*)&As[2*sr+1][k];
            #pragma unroll
            for (int c = 0; c < 4; ++c) {
                float4 w = *(float4*)&Ws[er + 32*c][k];
                acc[0][c] += a0.x*w.x + a0.y*w.y + a0.z*w.z + a0.w*w.w;
                acc[1][c] += a1.x*w.x + a1.y*w.y + a1.z*w.z + a1.w*w.w;
            }
        }
        __syncthreads();
    }
    #pragma unroll
    for (int si = 0; si < 2; ++si)
        #pragma unroll
        for (int c = 0; c < 4; ++c)
            out[OFF_SF + (long long)(r0 + 2*sr + si)*DD + e0 + er + 32*c] = acc[si][c];
}

// ---------------------------------------------------------------------------
// Kernel D: one block per (b,t1) row; fills that row of BOTH big masks
// (float4 streaming stores) plus the 8 tran_mask entries for the row.
// ---------------------------------------------------------------------------
__global__ __launch_bounds__(256) void mask_kernel(
    const int* __restrict__ ids_g,   // [B][T]
    const int* __restrict__ att,     // [32][256]
    float* __restrict__ out)
{
    const int blk = blockIdx.x;      // 0..B*T-1
    const int b  = blk / TT;
    const int t1 = blk % TT;
    const int tid = threadIdx.x;
    const int j1 = t1 / LL, i1 = t1 % LL;
    __shared__ int   ids_blk[LL];
    __shared__ float am_blk[LL];
    for (int i = tid; i < LL; i += 256) {
        ids_blk[i] = ids_g[b*TT + j1*LL + i];
        am_blk[i]  = (float)att[(b*SD + j1)*LSEC + 1 + i];
    }
    __syncthreads();
    const int   myid = ids_blk[i1];
    const float am1  = am_blk[i1];

    if (tid < SD)
        out[OFF_TM + (long long)blk*SD + tid] = (tid == j1) ? 1.f : 0.f;

    float* row4 = out + OFF_SMF + (long long)blk * TT;
    float* row5 = out + OFF_SEC + (long long)blk * TT;
    const int cstart = j1 * LL;
    for (int fq = tid; fq < TT/4; fq += 256) {
        int c = fq * 4;
        float4 v4, v5;
        float* pv4 = (float*)&v4; float* pv5 = (float*)&v5;
        #pragma unroll
        for (int u = 0; u < 4; ++u) {
            int i2 = c + u - cstart;
            bool in = (i2 >= 0) & (i2 < LL);
            int ii = in ? i2 : 0;
            pv4[u] = in ? ((ids_blk[ii] == myid) ? 1.f : 0.f) : 0.f;
            pv5[u] = in ? (am_blk[ii] * am1) : 0.f;
        }
        *(float4*)&row4[c] = v4;
        *(float4*)&row5[c] = v5;
    }
}

// ---------------------------------------------------------------------------
extern "C" void kernel_launch(void* const* d_in, const int* in_sizes, int n_in,
                              void* d_out, int out_size, void* d_ws, size_t ws_size,
                              hipStream_t stream)
{
    const float* atf  = (const float*)d_in[0];  // all_token_feature [32,256,768]
    const float* pf   = (const float*)d_in[1];  // pooled_feature    [32,768]
    const int*   att  = (const int*)  d_in[2];  // attention_mask    [32,256]
    const int*   ids  = (const int*)  d_in[3];  // sentence_mask     [4,8,254]
    const float* Wg2  = (const float*)d_in[4];  // W_g2 [768,768]
    const float* Wcls = (const float*)d_in[5];  // W_cls [2,768]
    const float* bcls = (const float*)d_in[6];  // b_cls [2]
    float* out = (float*)d_out;

    int*   wfirst = (int*)d_ws;                       // [400]
    int*   wlast  = wfirst + BD*MAXS;                 // [400]
    float* pooled = (float*)((char*)d_ws + 4096);     // [400][768] = 1.23 MB

    hipLaunchKernelGGL(prep_kernel, dim3(BD), dim3(256), 0, stream,
                       ids, pf, Wcls, bcls, out, wfirst, wlast);
    hipLaunchKernelGGL(pool_kernel, dim3(BD*MAXS), dim3(256), 0, stream,
                       atf, wfirst, wlast, pooled);
    hipLaunchKernelGGL(sf_gemm_kernel, dim3(25, 6), dim3(256), 0, stream,
                       pooled, Wg2, out);
    hipLaunchKernelGGL(mask_kernel, dim3(BD*TT), dim3(256), 0, stream,
                       ids, att, out);
}

// Round 2
// 106.229 us; speedup vs baseline: 1.1417x; 1.1417x over previous
//
#include <hip/hip_runtime.h>
#include <hip/hip_bf16.h>

// Problem geometry (fixed by the reference)
#define BD   4
#define SD   8
#define LSEC 256
#define LL   254
#define DD   768
#define MAXS 100
#define TT   (SD*LL)   // 2032

// Flat output offsets (float32 elements, reference return order)
#define OFF_SF  0LL                       // sentence_feature [4,100,768]   307200
#define OFF_TM  307200LL                  // tran_mask        [4,2032,8]     65024
#define OFF_TMS 372224LL                  // tran_mask_sec    [4,100,8]       3200
#define OFF_SMF 375424LL                  // sentence_mask_full [4,2032,2032] 16516096
#define OFF_SEC (375424LL + 16516096LL)   // section_mask_full  [4,2032,2032] 16516096
#define OFF_LOG 33407616LL                // logits1 [4,2]

// Mega-kernel block partition
#define NPREP 4
#define NGEMM 150          // 25 x 6
#define GEMM0 NPREP
#define MASK0 (NPREP + NGEMM)

// ---------------------------------------------------------------------------
// Kernel 1: per-(sentence, d-chunk) max pooling; block finds its own range.
// 4-way ILP over tokens (clamped index -> no branches in inner loop).
// ---------------------------------------------------------------------------
__global__ __launch_bounds__(256) void pool_kernel(
    const float* __restrict__ atf,     // [32][256][768]
    const int*   __restrict__ ids_g,   // [B][T], nondecreasing runs 1..100
    float* __restrict__ pooled)        // [400][768]
{
    const int sent = blockIdx.x;       // 0..399
    const int b    = sent / MAXS;
    const int sid  = sent % MAXS + 1;
    const int d0   = blockIdx.y << 8;  // 0,256,512
    const int tid  = threadIdx.x;

    __shared__ int sf, sl;
    if (tid == 0) { sf = TT; sl = -1; }
    __syncthreads();

    int lf = TT, lm = -1;
    for (int t = tid; t < TT; t += 256) {
        if (ids_g[b*TT + t] == sid) { lf = min(lf, t); lm = max(lm, t); }
    }
    atomicMin(&sf, lf);
    atomicMax(&sl, lm);
    __syncthreads();
    const int f = sf, l = sl;

    float m = 0.0f;                    // absent sentence id -> zero (ref isfinite mask)
    if (l >= 0) {
        float m0 = -INFINITY, m1 = -INFINITY, m2 = -INFINITY, m3 = -INFINITY;
        for (int t = f; t <= l; t += 4) {
            int t1 = min(t + 1, l), t2 = min(t + 2, l), t3 = min(t + 3, l);
            // token t -> atf row (b*8 + t/254), element 1 + t%254
            long long r0 = ((long long)(b*SD + t  / LL) * LSEC + 1 + t  % LL) * DD + d0 + tid;
            long long r1 = ((long long)(b*SD + t1 / LL) * LSEC + 1 + t1 % LL) * DD + d0 + tid;
            long long r2 = ((long long)(b*SD + t2 / LL) * LSEC + 1 + t2 % LL) * DD + d0 + tid;
            long long r3 = ((long long)(b*SD + t3 / LL) * LSEC + 1 + t3 % LL) * DD + d0 + tid;
            m0 = fmaxf(m0, atf[r0]);
            m1 = fmaxf(m1, atf[r1]);
            m2 = fmaxf(m2, atf[r2]);
            m3 = fmaxf(m3, atf[r3]);
        }
        m = fmaxf(fmaxf(m0, m1), fmaxf(m2, m3));
    }
    pooled[(long long)sent * DD + d0 + tid] = m;
}

// ---------------------------------------------------------------------------
// Kernel 2: mega kernel — block-partitioned into prep / gemm / mask work.
// ---------------------------------------------------------------------------
union SMem {
    struct { float As[16][68]; float Ws[128][68]; } g;                 // 39168 B
    struct { int ids[TT]; int counts[SD]; int starts[SD]; float red[256]; } p;
    struct { int ids[LL]; float am[LL]; } m;
};

__global__ __launch_bounds__(256) void mega_kernel(
    const float* __restrict__ pf,      // pooled_feature [32][768]
    const int*   __restrict__ att,     // [32][256]
    const int*   __restrict__ ids_g,   // [B][T]
    const float* __restrict__ Wg2,     // [768][768] row-major [e][d]
    const float* __restrict__ Wcls,    // [2][768]
    const float* __restrict__ bcls,    // [2]
    const float* __restrict__ pooled,  // [400][768] (workspace)
    float* __restrict__ out)
{
    __shared__ SMem sm;
    const int blk = blockIdx.x;
    const int tid = threadIdx.x;

    if (blk < NPREP) {
        // ---------------- prep: tran_mask_sec + logits1 for doc b ----------
        const int b = blk;
        for (int t = tid; t < TT; t += 256) sm.p.ids[t] = ids_g[b*TT + t];
        if (tid < SD) sm.p.counts[tid] = 0;
        __syncthreads();
        // distinct ids per section = run starts within the section
        for (int t = tid; t < TT; t += 256) {
            int j = t / LL;
            bool bnd = (t % LL == 0) || (sm.p.ids[t] != sm.p.ids[t-1]);
            if (bnd) atomicAdd(&sm.p.counts[j], 1);
        }
        __syncthreads();
        if (tid == 0) {
            int acc = 0;
            for (int j = 0; j < SD; ++j) { sm.p.starts[j] = acc; acc += sm.p.counts[j]; }
        }
        __syncthreads();
        for (int idx = tid; idx < MAXS*SD; idx += 256) {
            int r = idx / SD, j = idx % SD;
            float v = (r >= sm.p.starts[j] && r < sm.p.starts[j] + sm.p.counts[j]) ? 1.0f : 0.0f;
            out[OFF_TMS + (long long)b*(MAXS*SD) + idx] = v;
        }
        // logits1
        float acc0 = 0.f, acc1 = 0.f;
        #pragma unroll
        for (int k = 0; k < 3; ++k) {
            int d = tid + k*256;
            float mv = pf[(b*SD)*DD + d];
            #pragma unroll
            for (int j = 1; j < SD; ++j) mv = fmaxf(mv, pf[(b*SD + j)*DD + d]);
            acc0 += mv * Wcls[d];
            acc1 += mv * Wcls[DD + d];
        }
        sm.p.red[tid] = acc0; __syncthreads();
        for (int off = 128; off > 0; off >>= 1) { if (tid < off) sm.p.red[tid] += sm.p.red[tid+off]; __syncthreads(); }
        float l0 = sm.p.red[0];
        __syncthreads();
        sm.p.red[tid] = acc1; __syncthreads();
        for (int off = 128; off > 0; off >>= 1) { if (tid < off) sm.p.red[tid] += sm.p.red[tid+off]; __syncthreads(); }
        if (tid == 0) {
            out[OFF_LOG + b*2 + 0] = l0          + bcls[0];
            out[OFF_LOG + b*2 + 1] = sm.p.red[0] + bcls[1];
        }
    } else if (blk < MASK0) {
        // ---------------- gemm: sentence_feature = pooled @ Wg2^T ----------
        const int g  = blk - GEMM0;
        const int r0 = (g % 25) * 16;
        const int e0 = (g / 25) * 128;
        const int er = tid & 31;
        const int sr = tid >> 5;       // 0..7
        float acc[2][4] = {{0.f,0.f,0.f,0.f},{0.f,0.f,0.f,0.f}};

        for (int k0 = 0; k0 < DD; k0 += 64) {
            {   // stage A: 16x64 = 256 float4
                int i = tid >> 4, c4 = (tid & 15) * 4;
                *(float4*)&sm.g.As[i][c4] = *(const float4*)&pooled[(long long)(r0 + i)*DD + k0 + c4];
            }
            #pragma unroll
            for (int it = 0; it < 8; ++it) {   // stage W: 128x64 = 2048 float4
                int idx = tid + it*256;
                int row = idx >> 4, c4 = (idx & 15) * 4;
                *(float4*)&sm.g.Ws[row][c4] = *(const float4*)&Wg2[(long long)(e0 + row)*DD + k0 + c4];
            }
            __syncthreads();
            #pragma unroll
            for (int k = 0; k < 64; k += 4) {
                float4 a0 = *(float4*)&sm.g.As[2*sr][k];
                float4 a1 = *(float4*)&sm.g.As[2*sr+1][k];
                #pragma unroll
                for (int c = 0; c < 4; ++c) {
                    float4 w = *(float4*)&sm.g.Ws[er + 32*c][k];
                    acc[0][c] += a0.x*w.x + a0.y*w.y + a0.z*w.z + a0.w*w.w;
                    acc[1][c] += a1.x*w.x + a1.y*w.y + a1.z*w.z + a1.w*w.w;
                }
            }
            __syncthreads();
        }
        #pragma unroll
        for (int si = 0; si < 2; ++si)
            #pragma unroll
            for (int c = 0; c < 4; ++c)
                out[OFF_SF + (long long)(r0 + 2*sr + si)*DD + e0 + er + 32*c] = acc[si][c];
    } else {
        // ---------------- mask row: one (b,t1) row of both big masks -------
        const int blk2 = blk - MASK0;  // 0..B*T-1
        const int b  = blk2 / TT;
        const int t1 = blk2 % TT;
        const int j1 = t1 / LL, i1 = t1 % LL;
        for (int i = tid; i < LL; i += 256) {
            sm.m.ids[i] = ids_g[b*TT + j1*LL + i];
            sm.m.am[i]  = (float)att[(b*SD + j1)*LSEC + 1 + i];
        }
        __syncthreads();
        const int   myid = sm.m.ids[i1];
        const float am1  = sm.m.am[i1];

        if (tid < SD)
            out[OFF_TM + (long long)blk2*SD + tid] = (tid == j1) ? 1.f : 0.f;

        float* row4 = out + OFF_SMF + (long long)blk2 * TT;
        float* row5 = out + OFF_SEC + (long long)blk2 * TT;
        const int cstart = j1 * LL;
        for (int fq = tid; fq < TT/4; fq += 256) {
            int c = fq * 4;
            float4 v4, v5;
            float* pv4 = (float*)&v4; float* pv5 = (float*)&v5;
            #pragma unroll
            for (int u = 0; u < 4; ++u) {
                int i2 = c + u - cstart;
                bool in = (i2 >= 0) & (i2 < LL);
                int ii = in ? i2 : 0;
                pv4[u] = in ? ((sm.m.ids[ii] == myid) ? 1.f : 0.f) : 0.f;
                pv5[u] = in ? (sm.m.am[ii] * am1) : 0.f;
            }
            *(float4*)&row4[c] = v4;
            *(float4*)&row5[c] = v5;
        }
    }
}

// ---------------------------------------------------------------------------
extern "C" void kernel_launch(void* const* d_in, const int* in_sizes, int n_in,
                              void* d_out, int out_size, void* d_ws, size_t ws_size,
                              hipStream_t stream)
{
    const float* atf  = (const float*)d_in[0];  // all_token_feature [32,256,768]
    const float* pf   = (const float*)d_in[1];  // pooled_feature    [32,768]
    const int*   att  = (const int*)  d_in[2];  // attention_mask    [32,256]
    const int*   ids  = (const int*)  d_in[3];  // sentence_mask     [4,8,254]
    const float* Wg2  = (const float*)d_in[4];  // W_g2 [768,768]
    const float* Wcls = (const float*)d_in[5];  // W_cls [2,768]
    const float* bcls = (const float*)d_in[6];  // b_cls [2]
    float* out = (float*)d_out;

    float* pooled = (float*)d_ws;               // [400][768] = 1.23 MB

    hipLaunchKernelGGL(pool_kernel, dim3(BD*MAXS, 3), dim3(256), 0, stream,
                       atf, ids, pooled);
    hipLaunchKernelGGL(mega_kernel, dim3(MASK0 + BD*TT), dim3(256), 0, stream,
                       pf, att, ids, Wg2, Wcls, bcls, pooled, out);
}